// Round 1
// baseline (8012.810 us; speedup 1.0000x reference)
//
#include <hip/hip_runtime.h>
#include <hip/hip_cooperative_groups.h>

namespace cg = cooperative_groups;

typedef __bf16 bf16;
typedef __bf16 bf16x8 __attribute__((ext_vector_type(8)));
typedef float  f32x4  __attribute__((ext_vector_type(4)));

#define T_STEPS 128
#define BATCH   256
#define HD      1024
#define N4H     4096
#define EMB_D   128

__device__ __forceinline__ float fast_sigmoid(float x) {
    return 1.0f / (1.0f + __expf(-x));
}
__device__ __forceinline__ float fast_tanh(float x) {
    // tanh(x) = 1 - 2/(e^{2x}+1); saturates correctly for |x| large (inf -> 1/-1)
    return 1.0f - 2.0f / (__expf(2.0f * x) + 1.0f);
}

// ---------------- prep: P[v][n] = (emb[v] @ Wx_gate)[hcol] + b_gate[hcol],
// with n = 4*hcol + gate, gate order (g,i,f,o) ----------------
__global__ void build_P(const float* __restrict__ emb,
                        const float* __restrict__ Wgx, const float* __restrict__ Wix,
                        const float* __restrict__ Wfx, const float* __restrict__ Wox,
                        const float* __restrict__ bg,  const float* __restrict__ bi,
                        const float* __restrict__ bfv, const float* __restrict__ bo,
                        float* __restrict__ P)
{
    int n = blockIdx.x * 256 + threadIdx.x;     // 0..40959
    int v  = n >> 12;                           // / 4096
    int nn = n & (N4H - 1);
    int hcol = nn >> 2, gate = nn & 3;
    const float* Wx = (gate == 0) ? Wgx : (gate == 1) ? Wix : (gate == 2) ? Wfx : Wox;
    const float* bb = (gate == 0) ? bg  : (gate == 1) ? bi  : (gate == 2) ? bfv : bo;
    float s = bb[hcol];
    for (int e = 0; e < EMB_D; ++e)
        s += emb[v * EMB_D + e] * Wx[e * HD + hcol];
    P[n] = s;
}

// ---------------- prep: WhpT[n][k] = Wh_gate[k][hcol] as bf16 (transposed, permuted) ----
__global__ void build_W(const float* __restrict__ Wgh, const float* __restrict__ Wih,
                        const float* __restrict__ Wfh, const float* __restrict__ Woh,
                        bf16* __restrict__ WhpT)
{
    __shared__ float tile[64][65];
    int bid  = blockIdx.x;          // 0..1023
    int gate = bid >> 8;
    int t2   = bid & 255;
    int kt = t2 >> 4, ht = t2 & 15;
    const float* W = (gate == 0) ? Wgh : (gate == 1) ? Wih : (gate == 2) ? Wfh : Woh;
    int tid = threadIdx.x;
    #pragma unroll
    for (int it = 0; it < 16; ++it) {
        int idx = it * 256 + tid;
        int kk = idx >> 6, hh = idx & 63;
        tile[kk][hh] = W[(size_t)(kt * 64 + kk) * HD + ht * 64 + hh];
    }
    __syncthreads();
    #pragma unroll
    for (int it = 0; it < 16; ++it) {
        int idx = it * 256 + tid;
        int hh = idx >> 6, kk = idx & 63;
        int n = (ht * 64 + hh) * 4 + gate;
        WhpT[(size_t)n * HD + kt * 64 + kk] = (bf16)tile[kk][hh];
    }
}

// ---------------- main persistent cooperative kernel ----------------
// grid 256 blocks x 256 threads (1 block/CU). Block (mi,ni): mi=bid>>6 (batch
// tile of 64 rows), ni=bid&63 (16 h-columns = 64 gate-columns). Computes
// preT[n][m] = sum_k WhpT[n][k]*h[m][k]; MFMA D-layout puts the 4 gates of one
// (hcol,m) pair in one lane's 4 accumulator regs -> lane-local state update.
__global__ __launch_bounds__(256, 1)
void lstm_main(const int* __restrict__ x, const float* __restrict__ P,
               const bf16* __restrict__ WhpT, bf16* __restrict__ hbuf)
{
    __shared__ bf16 Alds[64][1032];   // weights, persistent across all steps (+8 pad)
    __shared__ bf16 Blds[64][136];    // h chunk, BK=128 (+8 pad)

    const int tid  = threadIdx.x;
    const int lane = tid & 63;
    const int wid  = tid >> 6;
    const int wn = wid >> 1, wm = wid & 1;   // 2x2 wave grid of 32x32 sub-tiles
    const int frow = lane & 15;
    const int kgrp = lane >> 4;
    const int bid = blockIdx.x;
    const int mi = bid >> 6;     // 0..3
    const int ni = bid & 63;     // 0..63

    // persistent A load: WhpT rows [ni*64, ni*64+64), all k (once)
    #pragma unroll
    for (int it = 0; it < 32; ++it) {
        int idx = it * 256 + tid;
        int row = idx >> 7, g = idx & 127;
        *(bf16x8*)&Alds[row][g * 8] =
            *(const bf16x8*)(WhpT + (size_t)(ni * 64 + row) * HD + g * 8);
    }

    float st[2][2] = {{0.f, 0.f}, {0.f, 0.f}};
    cg::grid_group grid = cg::this_grid();

    for (int t = 0; t < T_STEPS; ++t) {
        const bf16* hin  = hbuf + (size_t)(t & 1) * BATCH * HD;
        bf16*       hout = hbuf + (size_t)((t + 1) & 1) * BATCH * HD;

        // accumulator init = P[x[t][m]][4*hcol + r]  (r = gate = D reg index)
        f32x4 acc[2][2];
        int xv[2];
        #pragma unroll
        for (int fm = 0; fm < 2; ++fm)
            xv[fm] = x[t * BATCH + mi * 64 + wm * 32 + fm * 16 + frow];
        #pragma unroll
        for (int fn = 0; fn < 2; ++fn) {
            int nbase = (ni * 16 + wn * 8 + fn * 4 + kgrp) * 4;
            #pragma unroll
            for (int fm = 0; fm < 2; ++fm)
                acc[fn][fm] = *(const f32x4*)(P + (size_t)xv[fm] * N4H + nbase);
        }

        const bf16* Bsrc = hin + (size_t)(mi * 64) * HD;
        bf16x8 rb[4];
        // prologue: chunk 0 into regs
        #pragma unroll
        for (int i = 0; i < 4; ++i) {
            int idx = i * 256 + tid;
            int row = idx >> 4, g = idx & 15;
            rb[i] = *(const bf16x8*)(Bsrc + (size_t)row * HD + g * 8);
        }
        #pragma unroll
        for (int kc = 0; kc < 8; ++kc) {
            __syncthreads();            // prev compute done reading Blds
            #pragma unroll
            for (int i = 0; i < 4; ++i) {
                int idx = i * 256 + tid;
                int row = idx >> 4, g = idx & 15;
                *(bf16x8*)&Blds[row][g * 8] = rb[i];
            }
            if (kc < 7) {               // prefetch next chunk under the MFMAs
                #pragma unroll
                for (int i = 0; i < 4; ++i) {
                    int idx = i * 256 + tid;
                    int row = idx >> 4, g = idx & 15;
                    rb[i] = *(const bf16x8*)(Bsrc + (size_t)row * HD + (kc + 1) * 128 + g * 8);
                }
            }
            __syncthreads();
            #pragma unroll
            for (int ks = 0; ks < 4; ++ks) {
                bf16x8 af[2], bfr[2];
                #pragma unroll
                for (int fn = 0; fn < 2; ++fn)
                    af[fn] = *(const bf16x8*)&Alds[wn * 32 + fn * 16 + frow]
                                                  [kc * 128 + ks * 32 + kgrp * 8];
                #pragma unroll
                for (int fm = 0; fm < 2; ++fm)
                    bfr[fm] = *(const bf16x8*)&Blds[wm * 32 + fm * 16 + frow]
                                                   [ks * 32 + kgrp * 8];
                #pragma unroll
                for (int fn = 0; fn < 2; ++fn)
                    #pragma unroll
                    for (int fm = 0; fm < 2; ++fm)
                        acc[fn][fm] = __builtin_amdgcn_mfma_f32_16x16x32_bf16(
                            af[fn], bfr[fm], acc[fn][fm], 0, 0, 0);
            }
        }

        // gates + state update + h write (all lane-local)
        #pragma unroll
        for (int fn = 0; fn < 2; ++fn) {
            int hcol = ni * 16 + wn * 8 + fn * 4 + kgrp;
            #pragma unroll
            for (int fm = 0; fm < 2; ++fm) {
                int m = mi * 64 + wm * 32 + fm * 16 + frow;
                f32x4 pre = acc[fn][fm];
                float gg = fast_tanh(pre[0]);
                float ii = fast_sigmoid(pre[1]);
                float ff = fast_sigmoid(pre[2]);
                float oo = fast_sigmoid(pre[3]);
                float s = gg * ii + st[fn][fm] * ff;
                st[fn][fm] = s;
                hout[(size_t)m * HD + hcol] = (bf16)(fast_tanh(s) * oo);
            }
        }
        __threadfence();
        grid.sync();
    }
}

// ---------------- final projection: out[b][c] = h_T[b] @ Wph + bp ----------------
__global__ void proj_out(const bf16* __restrict__ h, const float* __restrict__ Wph,
                         const float* __restrict__ bp, float* __restrict__ out)
{
    __shared__ float red[256][10];
    int b = blockIdx.x, tid = threadIdx.x;
    float acc[10];
    #pragma unroll
    for (int c = 0; c < 10; ++c) acc[c] = 0.f;
    for (int k = tid; k < HD; k += 256) {
        float hv = (float)h[(size_t)b * HD + k];
        #pragma unroll
        for (int c = 0; c < 10; ++c)
            acc[c] += hv * Wph[k * 10 + c];
    }
    #pragma unroll
    for (int c = 0; c < 10; ++c) red[tid][c] = acc[c];
    __syncthreads();
    for (int s = 128; s > 0; s >>= 1) {
        if (tid < s) {
            #pragma unroll
            for (int c = 0; c < 10; ++c) red[tid][c] += red[tid + s][c];
        }
        __syncthreads();
    }
    if (tid < 10) out[b * 10 + tid] = red[0][tid] + bp[tid];
}

extern "C" void kernel_launch(void* const* d_in, const int* in_sizes, int n_in,
                              void* d_out, int out_size, void* d_ws, size_t ws_size,
                              hipStream_t stream)
{
    const int*   x   = (const int*)  d_in[0];
    const float* emb = (const float*)d_in[1];
    const float* Wgx = (const float*)d_in[2];
    const float* Wgh = (const float*)d_in[3];
    const float* Wix = (const float*)d_in[4];
    const float* Wih = (const float*)d_in[5];
    const float* Wfx = (const float*)d_in[6];
    const float* Wfh = (const float*)d_in[7];
    const float* Wox = (const float*)d_in[8];
    const float* Woh = (const float*)d_in[9];
    const float* bg  = (const float*)d_in[10];
    const float* bi  = (const float*)d_in[11];
    const float* bfv = (const float*)d_in[12];
    const float* bo  = (const float*)d_in[13];
    const float* Wph = (const float*)d_in[14];
    const float* bp  = (const float*)d_in[15];

    char* ws = (char*)d_ws;
    bf16*  WhpT = (bf16*)ws;                                   // 8 MB
    float* P    = (float*)(ws + 8388608);                      // 160 KB
    bf16*  hbuf = (bf16*)(ws + 8388608 + 163840);              // 2 x 512 KB

    // zero parity-0 h buffer (read at t=0; also the final-h buffer each call)
    hipMemsetAsync(hbuf, 0, (size_t)BATCH * HD * sizeof(bf16), stream);
    build_P<<<160, 256, 0, stream>>>(emb, Wgx, Wix, Wfx, Wox, bg, bi, bfv, bo, P);
    build_W<<<1024, 256, 0, stream>>>(Wgh, Wih, Wfh, Woh, WhpT);

    void* args[] = { (void*)&x, (void*)&P, (void*)&WhpT, (void*)&hbuf };
    hipLaunchCooperativeKernel((void*)lstm_main, dim3(256), dim3(256), args, 0, stream);

    proj_out<<<256, 256, 0, stream>>>(hbuf, Wph, bp, (float*)d_out);
}

// Round 2
// 2614.100 us; speedup vs baseline: 3.0652x; 3.0652x over previous
//
#include <hip/hip_runtime.h>
#include <hip/hip_cooperative_groups.h>

namespace cg = cooperative_groups;

typedef __bf16 bf16;
typedef __bf16 bf16x8 __attribute__((ext_vector_type(8)));
typedef float  f32x4  __attribute__((ext_vector_type(4)));

#define T_STEPS 128
#define BATCH   256
#define HD      1024
#define N4H     4096
#define EMB_D   128

__device__ __forceinline__ float fast_sigmoid(float x) {
    return 1.0f / (1.0f + __expf(-x));
}
__device__ __forceinline__ float fast_tanh(float x) {
    return 1.0f - 2.0f / (__expf(2.0f * x) + 1.0f);
}

// ---------------- prep: P[v][n] = (emb[v] @ Wx_gate)[hcol] + b_gate[hcol],
// with n = 4*hcol + gate, gate order (g,i,f,o) ----------------
__global__ void build_P(const float* __restrict__ emb,
                        const float* __restrict__ Wgx, const float* __restrict__ Wix,
                        const float* __restrict__ Wfx, const float* __restrict__ Wox,
                        const float* __restrict__ bg,  const float* __restrict__ bi,
                        const float* __restrict__ bfv, const float* __restrict__ bo,
                        float* __restrict__ P)
{
    int n = blockIdx.x * 256 + threadIdx.x;     // 0..40959
    int v  = n >> 12;                           // / 4096
    int nn = n & (N4H - 1);
    int hcol = nn >> 2, gate = nn & 3;
    const float* Wx = (gate == 0) ? Wgx : (gate == 1) ? Wix : (gate == 2) ? Wfx : Wox;
    const float* bb = (gate == 0) ? bg  : (gate == 1) ? bi  : (gate == 2) ? bfv : bo;
    float s = bb[hcol];
    for (int e = 0; e < EMB_D; ++e)
        s += emb[v * EMB_D + e] * Wx[e * HD + hcol];
    P[n] = s;
}

// ---------------- prep: WhpT[n][k] = Wh_gate[k][hcol] as bf16 (transposed, permuted) ----
__global__ void build_W(const float* __restrict__ Wgh, const float* __restrict__ Wih,
                        const float* __restrict__ Wfh, const float* __restrict__ Woh,
                        bf16* __restrict__ WhpT)
{
    __shared__ float tile[64][65];
    int bid  = blockIdx.x;          // 0..1023
    int gate = bid >> 8;
    int t2   = bid & 255;
    int kt = t2 >> 4, ht = t2 & 15;
    const float* W = (gate == 0) ? Wgh : (gate == 1) ? Wih : (gate == 2) ? Wfh : Woh;
    int tid = threadIdx.x;
    #pragma unroll
    for (int it = 0; it < 16; ++it) {
        int idx = it * 256 + tid;
        int kk = idx >> 6, hh = idx & 63;
        tile[kk][hh] = W[(size_t)(kt * 64 + kk) * HD + ht * 64 + hh];
    }
    __syncthreads();
    #pragma unroll
    for (int it = 0; it < 16; ++it) {
        int idx = it * 256 + tid;
        int hh = idx >> 6, kk = idx & 63;
        int n = (ht * 64 + hh) * 4 + gate;
        WhpT[(size_t)n * HD + kt * 64 + kk] = (bf16)tile[kk][hh];
    }
}

// ---------------- group barrier: 64 blocks sharing one batch-slice ----------------
// arrival: ACQ_REL fetch_add (releases this block's h stores device-wide);
// wait: relaxed spin + one acquire load (invalidate caches once on exit).
__device__ __forceinline__ void group_barrier(int* ctr, int* gen, int target, int nb)
{
    __syncthreads();   // compiler emits s_waitcnt vmcnt(0) -> h stores drained
    if (threadIdx.x == 0) {
        int old = __hip_atomic_fetch_add(ctr, 1, __ATOMIC_ACQ_REL, __HIP_MEMORY_SCOPE_AGENT);
        if (old == nb - 1) {
            __hip_atomic_store(ctr, 0, __ATOMIC_RELAXED, __HIP_MEMORY_SCOPE_AGENT);
            __hip_atomic_store(gen, target, __ATOMIC_RELEASE, __HIP_MEMORY_SCOPE_AGENT);
        } else {
            while (__hip_atomic_load(gen, __ATOMIC_RELAXED, __HIP_MEMORY_SCOPE_AGENT) < target)
                __builtin_amdgcn_s_sleep(1);
            (void)__hip_atomic_load(gen, __ATOMIC_ACQUIRE, __HIP_MEMORY_SCOPE_AGENT);
        }
    }
    __syncthreads();
}

// ---------------- main persistent cooperative kernel ----------------
// 256 blocks x 256 threads, 1 block/CU. Block (mi,ni): mi=bid>>6 (64 batch
// rows), ni=bid&63 (16 h-cols = 64 gate-cols). Weights persistent in LDS;
// B (h rows) read directly from global (no in-step syncthreads); 4 waves own
// 4 disjoint m-subtiles (no duplicate B reads). Sync only within the 64-block
// group that shares this mi.
__global__ __launch_bounds__(256, 1)
void lstm_main(const int* __restrict__ x, const float* __restrict__ P,
               const bf16* __restrict__ WhpT, bf16* __restrict__ hbuf,
               int* __restrict__ bar)
{
    __shared__ bf16 Alds[64][1032];   // weights, persistent (+8 pad)
    __shared__ bf16 hstage[64][24];   // h-out staging (+8 pad)

    const int tid  = threadIdx.x;
    const int lane = tid & 63;
    const int wid  = tid >> 6;        // 0..3 -> m sub-tile
    const int frow = lane & 15;
    const int kgrp = lane >> 4;
    const int bid = blockIdx.x;
    const int mi = bid >> 6;          // 0..3
    const int ni = bid & 63;          // 0..63

    // persistent A load: WhpT rows [ni*64, ni*64+64), all k (once)
    #pragma unroll
    for (int it = 0; it < 32; ++it) {
        int idx = it * 256 + tid;
        int row = idx >> 7, g = idx & 127;
        *(bf16x8*)&Alds[row][g * 8] =
            *(const bf16x8*)(WhpT + (size_t)(ni * 64 + row) * HD + g * 8);
    }
    __syncthreads();

    int* ctr = bar + mi * 64;
    int* gen = bar + mi * 64 + 32;

    const int m_loc = wid * 16 + frow;     // 0..63 local batch row
    const int mg    = mi * 64 + m_loc;     // global batch row

    float st[4] = {0.f, 0.f, 0.f, 0.f};

    for (int t = 0; t < T_STEPS; ++t) {
        const bf16* hin  = hbuf + (size_t)(t & 1) * BATCH * HD;
        bf16*       hout = hbuf + (size_t)((t + 1) & 1) * BATCH * HD;

        // accumulator init = P[x[t][m]][4*hcol + gate]
        int xv = x[t * BATCH + mg];
        f32x4 acc[4];
        #pragma unroll
        for (int fn = 0; fn < 4; ++fn)
            acc[fn] = *(const f32x4*)(P + (size_t)xv * N4H + (ni * 16 + fn * 4 + kgrp) * 4);

        const bf16* Brow = hin + (size_t)mg * HD;   // this lane's own batch row

        #pragma unroll
        for (int kc = 0; kc < 8; ++kc) {
            #pragma unroll
            for (int ks = 0; ks < 4; ++ks) {
                bf16x8 bfr = *(const bf16x8*)(Brow + kc * 128 + ks * 32 + kgrp * 8);
                #pragma unroll
                for (int fn = 0; fn < 4; ++fn) {
                    bf16x8 af = *(const bf16x8*)&Alds[fn * 16 + frow]
                                                     [kc * 128 + ks * 32 + kgrp * 8];
                    acc[fn] = __builtin_amdgcn_mfma_f32_16x16x32_bf16(af, bfr, acc[fn], 0, 0, 0);
                }
            }
        }

        // gates + state update (lane-local), stage h in LDS
        #pragma unroll
        for (int fn = 0; fn < 4; ++fn) {
            f32x4 pre = acc[fn];
            float gg = fast_tanh(pre[0]);
            float ii = fast_sigmoid(pre[1]);
            float ff = fast_sigmoid(pre[2]);
            float oo = fast_sigmoid(pre[3]);
            float s = gg * ii + st[fn] * ff;
            st[fn] = s;
            hstage[m_loc][fn * 4 + kgrp] = (bf16)(fast_tanh(s) * oo);
        }
        __syncthreads();
        // coalesced h store: 64 rows x 32B
        if (tid < 128) {
            int m = tid >> 1, half = tid & 1;
            bf16x8 v = *(const bf16x8*)&hstage[m][half * 8];
            *(bf16x8*)(hout + (size_t)(mi * 64 + m) * HD + ni * 16 + half * 8) = v;
        }
        group_barrier(ctr, gen, t + 1, 64);
    }
}

// ---------------- final projection: out[b][c] = h_T[b] @ Wph + bp ----------------
__global__ void proj_out(const bf16* __restrict__ h, const float* __restrict__ Wph,
                         const float* __restrict__ bp, float* __restrict__ out)
{
    __shared__ float red[256][10];
    int b = blockIdx.x, tid = threadIdx.x;
    float acc[10];
    #pragma unroll
    for (int c = 0; c < 10; ++c) acc[c] = 0.f;
    for (int k = tid; k < HD; k += 256) {
        float hv = (float)h[(size_t)b * HD + k];
        #pragma unroll
        for (int c = 0; c < 10; ++c)
            acc[c] += hv * Wph[k * 10 + c];
    }
    #pragma unroll
    for (int c = 0; c < 10; ++c) red[tid][c] = acc[c];
    __syncthreads();
    for (int s = 128; s > 0; s >>= 1) {
        if (tid < s) {
            #pragma unroll
            for (int c = 0; c < 10; ++c) red[tid][c] += red[tid + s][c];
        }
        __syncthreads();
    }
    if (tid < 10) out[b * 10 + tid] = red[0][tid] + bp[tid];
}

extern "C" void kernel_launch(void* const* d_in, const int* in_sizes, int n_in,
                              void* d_out, int out_size, void* d_ws, size_t ws_size,
                              hipStream_t stream)
{
    const int*   x   = (const int*)  d_in[0];
    const float* emb = (const float*)d_in[1];
    const float* Wgx = (const float*)d_in[2];
    const float* Wgh = (const float*)d_in[3];
    const float* Wix = (const float*)d_in[4];
    const float* Wih = (const float*)d_in[5];
    const float* Wfx = (const float*)d_in[6];
    const float* Wfh = (const float*)d_in[7];
    const float* Wox = (const float*)d_in[8];
    const float* Woh = (const float*)d_in[9];
    const float* bg  = (const float*)d_in[10];
    const float* bi  = (const float*)d_in[11];
    const float* bfv = (const float*)d_in[12];
    const float* bo  = (const float*)d_in[13];
    const float* Wph = (const float*)d_in[14];
    const float* bp  = (const float*)d_in[15];

    char* ws = (char*)d_ws;
    bf16*  WhpT = (bf16*)ws;                                   // 8 MB
    float* P    = (float*)(ws + 8388608);                      // 160 KB
    bf16*  hbuf = (bf16*)(ws + 8388608 + 163840);              // 2 x 512 KB
    int*   bar  = (int*)(ws + 8388608 + 163840 + 1048576);     // 4 groups x 256B

    // zero parity-0 h buffer (read at t=0; also the final-h buffer) + barrier state
    hipMemsetAsync(hbuf, 0, (size_t)BATCH * HD * sizeof(bf16), stream);
    hipMemsetAsync(bar, 0, 4 * 64 * sizeof(int), stream);
    build_P<<<160, 256, 0, stream>>>(emb, Wgx, Wix, Wfx, Wox, bg, bi, bfv, bo, P);
    build_W<<<1024, 256, 0, stream>>>(Wgh, Wih, Wfh, Woh, WhpT);

    void* args[] = { (void*)&x, (void*)&P, (void*)&WhpT, (void*)&hbuf, (void*)&bar };
    hipLaunchCooperativeKernel((void*)lstm_main, dim3(256), dim3(256), args, 0, stream);

    proj_out<<<256, 256, 0, stream>>>(hbuf, Wph, bp, (float*)d_out);
}